// Round 7
// baseline (232.605 us; speedup 1.0000x reference)
//
#include <hip/hip_runtime.h>

// IF neuron, multi-step, hard reset:
//   h_t = x_t + v_{t-1};  s_t = (h_t - 1.0 >= 0);  v_t = s_t ? 0 : h_t
//
// R6: store/load queue separation. vmcnt retires IN ORDER, so in previous
// rounds every wait-for-load also drained all older spike stores -> ~3.6
// TB/s wall regardless of prefetch depth (R3/R5 neutral). Fix: spikes are
// 0/1, so pack each thread's entire output into 8 VGPRs of bitmasks.
// Phase 1 (t-loop): loads ONLY in the vmem queue (C=4 independent float2
// columns + 2-slot t-rotation -> MLP up to 8). Phase 2 (epilogue): unpack
// bits -> 0.0/1.0 and fire-and-forget NT stores, drained at kernel end
// (fillBuffer-style, 6.7 TB/s pure-store regime).

typedef float v2f __attribute__((ext_vector_type(2)));

template <int T, int C>
__global__ __launch_bounds__(256) void if_node_bitpack(
    const float* __restrict__ x,    // (T, N)
    const float* __restrict__ v0,   // (N,)
    float* __restrict__ out,        // (T, N)
    long q)                         // column stride in float2 elems = (N/2)/C
{
    static_assert(T <= 32, "bitmask is 32-bit");
    long i = (long)blockIdx.x * blockDim.x + threadIdx.x;
    if (i >= q) return;

    const v2f* __restrict__ x2 = (const v2f*)x;
    v2f*       __restrict__ o2 = (v2f*)out;
    const v2f* __restrict__ vv = (const v2f*)v0;

    const long n2 = q * C;

    v2f v[C];
    unsigned mx[C], my[C];
#pragma unroll
    for (int c = 0; c < C; ++c) {
        v[c] = vv[i + (long)c * q];
        mx[c] = 0u;
        my[c] = 0u;
    }

    // 2-slot rotating t-buffer; queue contains only loads in this phase.
    v2f buf[2][C];
#pragma unroll
    for (int c = 0; c < C; ++c)
        buf[0][c] = x2[i + (long)c * q];

#pragma unroll
    for (int t = 0; t < T; ++t) {
        const int cur = t & 1;
        if (t + 1 < T) {
#pragma unroll
            for (int c = 0; c < C; ++c)
                buf[cur ^ 1][c] = x2[(long)(t + 1) * n2 + i + (long)c * q];
        }
#pragma unroll
        for (int c = 0; c < C; ++c) {
            float hx = buf[cur][c].x + v[c].x;
            float hy = buf[cur][c].y + v[c].y;
            bool sx = (hx - 1.0f) >= 0.0f;
            bool sy = (hy - 1.0f) >= 0.0f;
            mx[c] |= sx ? (1u << t) : 0u;
            my[c] |= sy ? (1u << t) : 0u;
            v[c].x = sx ? 0.0f : hx;
            v[c].y = sy ? 0.0f : hy;
        }
    }

    // Epilogue: pure stores, never waited on inside the kernel.
#pragma unroll
    for (int t = 0; t < T; ++t) {
#pragma unroll
        for (int c = 0; c < C; ++c) {
            v2f s;
            s.x = ((mx[c] >> t) & 1u) ? 1.0f : 0.0f;
            s.y = ((my[c] >> t) & 1u) ? 1.0f : 0.0f;
            __builtin_nontemporal_store(s, &o2[(long)t * n2 + i + (long)c * q]);
        }
    }
}

// Fallbacks for shapes the fast path doesn't cover.
__global__ __launch_bounds__(256) void if_node_f2_generic(
    const float* __restrict__ x, const float* __restrict__ v0,
    float* __restrict__ out, long n2, int T)
{
    long i = (long)blockIdx.x * blockDim.x + threadIdx.x;
    if (i >= n2) return;
    const v2f* x2 = (const v2f*)x;
    v2f*       o2 = (v2f*)out;
    v2f v = ((const v2f*)v0)[i];
    for (int t = 0; t < T; ++t) {
        v2f xv = x2[(long)t * n2 + i];
        float hx = xv.x + v.x;
        float hy = xv.y + v.y;
        bool sx = (hx - 1.0f) >= 0.0f;
        bool sy = (hy - 1.0f) >= 0.0f;
        v2f s;
        s.x = sx ? 1.0f : 0.0f;
        s.y = sy ? 1.0f : 0.0f;
        v.x = sx ? 0.0f : hx;
        v.y = sy ? 0.0f : hy;
        o2[(long)t * n2 + i] = s;
    }
}

__global__ __launch_bounds__(256) void if_node_scalar(
    const float* __restrict__ x, const float* __restrict__ v0,
    float* __restrict__ out, long n, int T)
{
    long i = (long)blockIdx.x * blockDim.x + threadIdx.x;
    if (i >= n) return;
    float v = v0[i];
    for (int t = 0; t < T; ++t) {
        float h = x[(long)t * n + i] + v;
        bool s = (h - 1.0f) >= 0.0f;
        out[(long)t * n + i] = s ? 1.0f : 0.0f;
        v = s ? 0.0f : h;
    }
}

extern "C" void kernel_launch(void* const* d_in, const int* in_sizes, int n_in,
                              void* d_out, int out_size, void* d_ws, size_t ws_size,
                              hipStream_t stream) {
    const float* x  = (const float*)d_in[0];   // (T, B, D) fp32
    const float* v0 = (const float*)d_in[1];   // (B, D) fp32
    float* out = (float*)d_out;                // (T, B, D) fp32

    long n = in_sizes[1];                      // B*D
    int  T = (int)(in_sizes[0] / n);           // 32

    int block = 256;
    constexpr int C = 4;
    if (T == 32 && (n % (2 * C)) == 0) {
        long n2 = n >> 1;          // float2 elements
        long q  = n2 / C;          // per-column float2 elements
        long grid = (q + block - 1) / block;
        if_node_bitpack<32, C><<<dim3((unsigned)grid), dim3(block), 0, stream>>>(
            x, v0, out, q);
    } else if ((n & 1) == 0) {
        long n2 = n >> 1;
        long grid = (n2 + block - 1) / block;
        if_node_f2_generic<<<dim3((unsigned)grid), dim3(block), 0, stream>>>(
            x, v0, out, n2, T);
    } else {
        long grid = (n + block - 1) / block;
        if_node_scalar<<<dim3((unsigned)grid), dim3(block), 0, stream>>>(
            x, v0, out, n, T);
    }
}